// Round 12
// baseline (147.912 us; speedup 1.0000x reference)
//
#include <hip/hip_runtime.h>

// PointNet 3-NN feature interpolation, v12: fused wave-cooperative scan.
// pack_points: xyz1 -> packed {2x,2y,2z,norm} float4 (1 MB/batch, L2-resident).
// knn3_wave8 : wave = 8 queries; lanes partition all N pts; phase A (first
//              1024 pts) unconditional lex top-3 -> in-register tau via value
//              butterfly; phase B filtered (d<=tau); final lex butterfly;
//              weights written inline. Depth-2 prefetch.
// interp     : per-(b,d) row staged in LDS, gather+weighted-sum.

constexpr int QW    = 8;          // queries per wave (divides S)
constexpr int TAUIT = 16;         // phase-A iterations (16*64 = 1024 pts)
constexpr float DINF = 3.4e38f;
constexpr int   ISENT = 0x7fffffff;

// guarded lexicographic (d, idx) insert
__device__ __forceinline__ void ins_lex(float& d0, float& d1, float& d2,
                                        int& i0, int& i1, int& i2,
                                        float d, int n) {
    bool l2 = (d < d2) || (d == d2 && n < i2);
    if (l2) {
        bool l1 = (d < d1) || (d == d1 && n < i1);
        bool l0 = (d < d0) || (d == d0 && n < i0);
        d2 = l1 ? d1 : d;  i2 = l1 ? i1 : n;
        d1 = l0 ? d0 : (l1 ? d : d1);
        i1 = l0 ? i0 : (l1 ? n : i1);
        d0 = l0 ? d  : d0; i0 = l0 ? n : i0;
    }
}

// branchless lexicographic insert
__device__ __forceinline__ void ins_lex_nb(float& d0, float& d1, float& d2,
                                           int& i0, int& i1, int& i2,
                                           float d, int n) {
    bool l2 = (d < d2) || (d == d2 && n < i2);
    bool l1 = (d < d1) || (d == d1 && n < i1);
    bool l0 = (d < d0) || (d == d0 && n < i0);
    float nd2 = l1 ? d1 : (l2 ? d : d2);
    int   ni2 = l1 ? i1 : (l2 ? n : i2);
    float nd1 = l0 ? d0 : (l1 ? d : d1);
    int   ni1 = l0 ? i0 : (l1 ? n : i1);
    d0 = l0 ? d : d0;  i0 = l0 ? n : i0;
    d1 = nd1; d2 = nd2; i1 = ni1; i2 = ni2;
}

// value-only top-3 insert (for the tau butterfly)
__device__ __forceinline__ void ins_v(float& d0, float& d1, float& d2, float d) {
    bool c0 = d < d0, c1 = d < d1, c2 = d < d2;
    float n2 = c1 ? d1 : (c2 ? d : d2);
    float n1 = c0 ? d0 : (c1 ? d : d1);
    d0 = c0 ? d : d0; d1 = n1; d2 = n2;
}

// pk[b*N+n] = {2x, 2y, 2z, (x*x + y*y) + z*z}. 2x exact (pow2 scale);
// (qx*2x + qy*2y) + qz*2z rounds bit-identically to 2*((qx*x+qy*y)+qz*z).
__global__ __launch_bounds__(256)
void pack_points(const float* __restrict__ xyz1, float4* __restrict__ pk,
                 int B, int N)
{
#pragma clang fp contract(off)
    int t = blockIdx.x * 256 + threadIdx.x;
    if (t >= B * N) return;
    int b = t / N, n = t - b * N;
    const float* __restrict__ bx = xyz1 + (size_t)b * 3 * N;
    float x = bx[n], y = bx[N + n], z = bx[2 * N + n];
    pk[t] = make_float4(x + x, y + y, z + z, (x * x + y * y) + z * z);
}

__global__ __launch_bounds__(256)
void knn3_wave8(const float4* __restrict__ pk, const float* __restrict__ xyz2,
                int B, int N, int S,
                int* __restrict__ idx0, int* __restrict__ idx1,
                int* __restrict__ idx2,
                float* __restrict__ w0, float* __restrict__ w1,
                float* __restrict__ w2)
{
#pragma clang fp contract(off)
    const int lane = threadIdx.x & 63;
    const int wid  = (blockIdx.x * 256 + threadIdx.x) >> 6;
    const int qb   = wid * QW;
    const int b    = qb / S;                 // QW | S -> wave-uniform
    const int sb   = qb - b * S;

    const float* __restrict__ q2p = xyz2 + (size_t)b * 3 * S;
    float qx[QW], qy[QW], qz[QW], qs[QW];
#pragma unroll
    for (int j = 0; j < QW; ++j) {           // wave-uniform addrs -> s_load
        qx[j] = q2p[sb + j];
        qy[j] = q2p[S + sb + j];
        qz[j] = q2p[2 * S + sb + j];
        qs[j] = (qx[j] * qx[j] + qy[j] * qy[j]) + qz[j] * qz[j];
    }

    const float4* __restrict__ pb = pk + (size_t)b * N;
    float d0[QW], d1[QW], d2[QW];
    int   i0[QW], i1[QW], i2[QW];
#pragma unroll
    for (int j = 0; j < QW; ++j) {
        d0[j] = d1[j] = d2[j] = DINF;
        i0[j] = i1[j] = i2[j] = ISENT;
    }

    const int NIT = N / 64;                  // 128
    float4 c0 = pb[lane];
    float4 c1 = pb[lane + 64];
    int it = 0;

    // ---- phase A: first TAUIT iterations, unconditional branchless insert
    for (; it < TAUIT; it += 2) {
        float4 n0 = pb[lane + 64 * (it + 2)];   // always < NIT (16+3 << 128)
        float4 n1 = pb[lane + 64 * (it + 3)];
        const int na = lane + 64 * it;
        const int nb_ = na + 64;
#pragma unroll
        for (int j = 0; j < QW; ++j) {
            float da = (qs[j] + c0.w) - ((qx[j] * c0.x + qy[j] * c0.y) + qz[j] * c0.z);
            ins_lex_nb(d0[j], d1[j], d2[j], i0[j], i1[j], i2[j], da, na);
            float db = (qs[j] + c1.w) - ((qx[j] * c1.x + qy[j] * c1.y) + qz[j] * c1.z);
            ins_lex_nb(d0[j], d1[j], d2[j], i0[j], i1[j], i2[j], db, nb_);
        }
        c0 = n0; c1 = n1;
    }

    // ---- in-register tau: 3rd-smallest value over the first 1024 points
    float tauv[QW];
#pragma unroll
    for (int j = 0; j < QW; ++j) {
        float t0 = d0[j], t1 = d1[j], t2 = d2[j];
#pragma unroll
        for (int m = 32; m >= 1; m >>= 1) {
            float a0 = __shfl_xor(t0, m);
            float a1 = __shfl_xor(t1, m);
            float a2 = __shfl_xor(t2, m);
            ins_v(t0, t1, t2, a0);
            ins_v(t0, t1, t2, a1);
            ins_v(t0, t1, t2, a2);
        }
        tauv[j] = t2;                         // tau >= global d2: exact bound
    }

    // ---- phase B: remaining points, filtered insert (d <= tau)
    for (; it + 3 < NIT; it += 2) {
        float4 n0 = pb[lane + 64 * (it + 2)];
        float4 n1 = pb[lane + 64 * (it + 3)];
        const int na = lane + 64 * it;
        const int nb_ = na + 64;
#pragma unroll
        for (int j = 0; j < QW; ++j) {
            float da = (qs[j] + c0.w) - ((qx[j] * c0.x + qy[j] * c0.y) + qz[j] * c0.z);
            if (__builtin_expect(da <= tauv[j], 0))
                ins_lex(d0[j], d1[j], d2[j], i0[j], i1[j], i2[j], da, na);
            float db = (qs[j] + c1.w) - ((qx[j] * c1.x + qy[j] * c1.y) + qz[j] * c1.z);
            if (__builtin_expect(db <= tauv[j], 0))
                ins_lex(d0[j], d1[j], d2[j], i0[j], i1[j], i2[j], db, nb_);
        }
        c0 = n0; c1 = n1;
    }
    {   // tail: last two iterations (no prefetch)
        const int na = lane + 64 * it;
        const int nb_ = na + 64;
#pragma unroll
        for (int j = 0; j < QW; ++j) {
            float da = (qs[j] + c0.w) - ((qx[j] * c0.x + qy[j] * c0.y) + qz[j] * c0.z);
            if (__builtin_expect(da <= tauv[j], 0))
                ins_lex(d0[j], d1[j], d2[j], i0[j], i1[j], i2[j], da, na);
            float db = (qs[j] + c1.w) - ((qx[j] * c1.x + qy[j] * c1.y) + qz[j] * c1.z);
            if (__builtin_expect(db <= tauv[j], 0))
                ins_lex(d0[j], d1[j], d2[j], i0[j], i1[j], i2[j], db, nb_);
        }
    }

    // ---- lexicographic butterfly: exact top-3 (order-independent ties)
#pragma unroll
    for (int m = 32; m >= 1; m >>= 1) {
#pragma unroll
        for (int j = 0; j < QW; ++j) {
            float a0 = __shfl_xor(d0[j], m);
            float a1 = __shfl_xor(d1[j], m);
            float a2 = __shfl_xor(d2[j], m);
            int   b0 = __shfl_xor(i0[j], m);
            int   b1 = __shfl_xor(i1[j], m);
            int   b2 = __shfl_xor(i2[j], m);
            ins_lex_nb(d0[j], d1[j], d2[j], i0[j], i1[j], i2[j], a0, b0);
            ins_lex_nb(d0[j], d1[j], d2[j], i0[j], i1[j], i2[j], a1, b1);
            ins_lex_nb(d0[j], d1[j], d2[j], i0[j], i1[j], i2[j], a2, b2);
        }
    }

#pragma unroll
    for (int j = 0; j < QW; ++j) {
        if (lane == j) {                      // static j: no dynamic indexing
            const int q = qb + j;
            float r0 = 1.0f / (d0[j] + 1e-8f);
            float r1 = 1.0f / (d1[j] + 1e-8f);
            float r2 = 1.0f / (d2[j] + 1e-8f);
            float sum = (r0 + r1) + r2;       // np sum order
            idx0[q] = i0[j]; idx1[q] = i1[j]; idx2[q] = i2[j];
            w0[q] = r0 / sum; w1[q] = r1 / sum; w2[q] = r2 / sum;
        }
    }
}

__global__ __launch_bounds__(256)
void interp_kernel(const float* __restrict__ points1,
                   const int* __restrict__ idx0, const int* __restrict__ idx1,
                   const int* __restrict__ idx2,
                   const float* __restrict__ w0, const float* __restrict__ w1,
                   const float* __restrict__ w2,
                   float* __restrict__ out, int N, int S, int D)
{
#pragma clang fp contract(off)
    __shared__ float row[8192];
    const int bd = blockIdx.x;
    const int b  = bd / D;
    const float* __restrict__ src = points1 + (size_t)bd * N;

    for (int i = threadIdx.x * 4; i < N; i += blockDim.x * 4) {
        *reinterpret_cast<float4*>(&row[i]) =
            *reinterpret_cast<const float4*>(src + i);
    }
    __syncthreads();

    float* __restrict__ dst = out + (size_t)bd * S;
    const int qb = b * S;
    for (int s = threadIdx.x; s < S; s += blockDim.x) {
        int q = qb + s;
        float a = row[idx0[q]] * w0[q];
        float c = row[idx1[q]] * w1[q];
        float e = row[idx2[q]] * w2[q];
        dst[s] = (a + c) + e;                 // np sum order
    }
}

extern "C" void kernel_launch(void* const* d_in, const int* in_sizes, int n_in,
                              void* d_out, int out_size, void* d_ws, size_t ws_size,
                              hipStream_t stream) {
    const float* xyz1    = (const float*)d_in[0];
    const float* xyz2    = (const float*)d_in[1];
    const float* points1 = (const float*)d_in[2];
    float* out = (float*)d_out;

    const int B = 8;
    const int N = in_sizes[0] / (3 * B);
    const int S = in_sizes[1] / (3 * B);
    const int D = in_sizes[2] / (B * N);
    const int BS = B * S;

    // ws: pk (16B aligned) | idx0..2 | w0..2   (~1.4 MB total)
    float4* pk   = (float4*)d_ws;
    int*    idx0 = (int*)(pk + (size_t)B * N);
    int*    idx1 = idx0 + BS;
    int*    idx2 = idx1 + BS;
    float*  w0   = (float*)(idx2 + BS);
    float*  w1   = w0 + BS;
    float*  w2   = w1 + BS;

    pack_points<<<(B * N + 255) / 256, 256, 0, stream>>>(xyz1, pk, B, N);

    const int nWave   = BS / QW;              // 2048 waves
    const int nBlocks = nWave / 4;            // 512 blocks (4 waves each)
    knn3_wave8<<<nBlocks, 256, 0, stream>>>(pk, xyz2, B, N, S,
                                            idx0, idx1, idx2, w0, w1, w2);

    interp_kernel<<<B * D, 256, 0, stream>>>(points1, idx0, idx1, idx2,
                                             w0, w1, w2, out, N, S, D);
}

// Round 13
// 99.041 us; speedup vs baseline: 1.4935x; 1.4935x over previous
//
#include <hip/hip_runtime.h>

// PointNet 3-NN feature interpolation, v13.
// pack_points: xyz1 -> packed {2x,2y,2z,norm} float4 (1 MB/batch, L2-resident).
// knn3_tau   : stage 64 pk pts/block, value-only top-3 -> 16 sub-partials.
// tau3_merge : tau[q] = 3rd-smallest over first 1024 pts.
// knn3_main  : Q=2 queries/thread, 256-pt pk chunks staged to LDS (plain copy),
//              4-deep prefetch pipeline, filter d<=tau, 32 partial slots.
// knn3_merge : merge partial top-3s (ascending slots), weights.
// interp     : per-(b,d) row staged in LDS, gather+weighted-sum.

constexpr int QT   = 256;    // threads per block
constexpr int SCS  = 64;     // tau sub-chunk points
constexpr int NSUB = 16;     // tau sub-chunks (1024 pts total)
constexpr float DINF = 3.4e38f;

__device__ __forceinline__ void insert3b(float& d0, float& d1, float& d2,
                                         int& i0, int& i1, int& i2,
                                         float d, int n) {
    bool c0 = d < d0, c1 = d < d1, c2 = d < d2;
    float nd2 = c1 ? d1 : (c2 ? d : d2);
    int   ni2 = c1 ? i1 : (c2 ? n : i2);
    float nd1 = c0 ? d0 : (c1 ? d : d1);
    int   ni1 = c0 ? i0 : (c1 ? n : i1);
    float nd0 = c0 ? d  : d0;
    int   ni0 = c0 ? n  : i0;
    d0 = nd0; d1 = nd1; d2 = nd2;
    i0 = ni0; i1 = ni1; i2 = ni2;
}

// value-only top-3 insert
__device__ __forceinline__ void ins_v(float& d0, float& d1, float& d2, float d) {
    bool c0 = d < d0, c1 = d < d1, c2 = d < d2;
    float n2 = c1 ? d1 : (c2 ? d : d2);
    float n1 = c0 ? d0 : (c1 ? d : d1);
    d0 = c0 ? d : d0; d1 = n1; d2 = n2;
}

// pk[b*N+n] = {2x, 2y, 2z, (x*x + y*y) + z*z}. 2x exact (pow2 scale);
// (qx*2x + qy*2y) + qz*2z rounds bit-identically to 2*((qx*x+qy*y)+qz*z);
// norm in np sum order. Same packed values as v4/v10 (both passed).
__global__ __launch_bounds__(256)
void pack_points(const float* __restrict__ xyz1, float4* __restrict__ pk,
                 int B, int N)
{
#pragma clang fp contract(off)
    int t = blockIdx.x * 256 + threadIdx.x;
    if (t >= B * N) return;
    int b = t / N, n = t - b * N;
    const float* __restrict__ bx = xyz1 + (size_t)b * 3 * N;
    float x = bx[n], y = bx[N + n], z = bx[2 * N + n];
    pk[t] = make_float4(x + x, y + y, z + z, (x * x + y * y) + z * z);
}

__global__ __launch_bounds__(256)
void knn3_tau(const float4* __restrict__ pk, const float* __restrict__ xyz2,
              int B, int N, int S, int BS,
              float* __restrict__ sd0, float* __restrict__ sd1,
              float* __restrict__ sd2)
{
#pragma clang fp contract(off)
    __shared__ float4 spt[SCS];
    const int tid = threadIdx.x;
    const int q   = blockIdx.x * QT + tid;
    const int c   = blockIdx.y;               // 0..NSUB-1
    const int b   = q / S;                    // QT | S
    const int s   = q - b * S;

    const float4* __restrict__ src = pk + (size_t)b * N + c * SCS;
    if (tid < SCS) spt[tid] = src[tid];
    __syncthreads();

    const float* __restrict__ q2p = xyz2 + (size_t)b * 3 * S;
    const float qx = q2p[s];
    const float qy = q2p[S + s];
    const float qz = q2p[2 * S + s];
    const float qss = (qx * qx + qy * qy) + qz * qz;

    float d0 = DINF, d1 = DINF, d2 = DINF;
#pragma unroll 8
    for (int k = 0; k < SCS; ++k) {
        float4 p = spt[k];
        float dot2 = (qx * p.x + qy * p.y) + qz * p.z;   // == 2*dot, exact
        float d    = (qss + p.w) - dot2;
        ins_v(d0, d1, d2, d);
    }
    const size_t off = (size_t)c * BS + q;
    sd0[off] = d0; sd1[off] = d1; sd2[off] = d2;
}

__global__ __launch_bounds__(256)
void tau3_merge(const float* __restrict__ sd0, const float* __restrict__ sd1,
                const float* __restrict__ sd2, int BS,
                float* __restrict__ tau)
{
    const int q = blockIdx.x * 256 + threadIdx.x;
    if (q >= BS) return;
    float d0 = DINF, d1 = DINF, d2 = DINF;
#pragma unroll
    for (int c = 0; c < NSUB; ++c) {
        const size_t off = (size_t)c * BS + q;
        ins_v(d0, d1, d2, sd0[off]);
        ins_v(d0, d1, d2, sd1[off]);
        ins_v(d0, d1, d2, sd2[off]);
    }
    tau[q] = d2;
}

// Q=2 queries/thread; cs-pt pk chunk staged by plain float4 copy.
__global__ __launch_bounds__(256)
void knn3_main(const float4* __restrict__ pk, const float* __restrict__ xyz2,
               const float* __restrict__ tau,
               int B, int N, int S, int BS, int cs,
               float* __restrict__ pd0, float* __restrict__ pd1,
               float* __restrict__ pd2,
               int* __restrict__ pi0, int* __restrict__ pi1,
               int* __restrict__ pi2)
{
#pragma clang fp contract(off)
    __shared__ float4 spt[512];               // cs <= 512
    const int tid = threadIdx.x;
    const int q0  = blockIdx.x * (2 * QT) + tid;
    const int q1  = q0 + QT;
    const int c   = blockIdx.y;
    const int b   = q0 / S;                   // 512 | S -> uniform per block
    const int s0  = q0 - b * S;
    const int n0  = c * cs;

    const float4* __restrict__ src = pk + (size_t)b * N + n0;
    for (int i = tid; i < cs; i += QT) spt[i] = src[i];
    __syncthreads();

    const float* __restrict__ q2p = xyz2 + (size_t)b * 3 * S;
    const float qxA = q2p[s0],          qxB = q2p[s0 + QT];
    const float qyA = q2p[S + s0],      qyB = q2p[S + s0 + QT];
    const float qzA = q2p[2 * S + s0],  qzB = q2p[2 * S + s0 + QT];
    const float qsA = (qxA * qxA + qyA * qyA) + qzA * qzA;
    const float qsB = (qxB * qxB + qyB * qyB) + qzB * qzB;
    const float tA  = tau[q0];
    const float tB  = tau[q1];

    float dA0 = DINF, dA1 = DINF, dA2 = DINF;
    float dB0 = DINF, dB1 = DINF, dB2 = DINF;
    int   iA0 = 0, iA1 = 0, iA2 = 0;
    int   iB0 = 0, iB1 = 0, iB2 = 0;

    // 4-deep prefetch pipeline (v9-proven schedule), 2 queries per point
    float4 pa = spt[0], pb = spt[1], pc = spt[2], pd_ = spt[3];
    int k = 0;
    for (; k + 4 < cs; k += 4) {
        float4 na = spt[k + 4];
        float4 nb = spt[k + 5];
        float4 nc = spt[k + 6];
        float4 nd = spt[k + 7];
#pragma unroll
        for (int u = 0; u < 4; ++u) {
            float4 p = (u == 0) ? pa : (u == 1) ? pb : (u == 2) ? pc : pd_;
            const int n = n0 + k + u;
            float da = (qsA + p.w) - ((qxA * p.x + qyA * p.y) + qzA * p.z);
            if (__builtin_expect(da <= tA, 0))
                insert3b(dA0, dA1, dA2, iA0, iA1, iA2, da, n);
            float db = (qsB + p.w) - ((qxB * p.x + qyB * p.y) + qzB * p.z);
            if (__builtin_expect(db <= tB, 0))
                insert3b(dB0, dB1, dB2, iB0, iB1, iB2, db, n);
        }
        pa = na; pb = nb; pc = nc; pd_ = nd;
    }
    {   // tail group
#pragma unroll
        for (int u = 0; u < 4; ++u) {
            float4 p = (u == 0) ? pa : (u == 1) ? pb : (u == 2) ? pc : pd_;
            const int n = n0 + k + u;
            float da = (qsA + p.w) - ((qxA * p.x + qyA * p.y) + qzA * p.z);
            if (__builtin_expect(da <= tA, 0))
                insert3b(dA0, dA1, dA2, iA0, iA1, iA2, da, n);
            float db = (qsB + p.w) - ((qxB * p.x + qyB * p.y) + qzB * p.z);
            if (__builtin_expect(db <= tB, 0))
                insert3b(dB0, dB1, dB2, iB0, iB1, iB2, db, n);
        }
    }

    const size_t offA = (size_t)c * BS + q0;
    const size_t offB = (size_t)c * BS + q1;
    pd0[offA] = dA0; pd1[offA] = dA1; pd2[offA] = dA2;
    pi0[offA] = iA0; pi1[offA] = iA1; pi2[offA] = iA2;
    pd0[offB] = dB0; pd1[offB] = dB1; pd2[offB] = dB2;
    pi0[offB] = iB0; pi1[offB] = iB1; pi2[offB] = iB2;
}

__global__ __launch_bounds__(256)
void knn3_merge(const float* __restrict__ pd0, const float* __restrict__ pd1,
                const float* __restrict__ pd2,
                const int* __restrict__ pi0, const int* __restrict__ pi1,
                const int* __restrict__ pi2,
                int nPart, int BS,
                int* __restrict__ idx0, int* __restrict__ idx1, int* __restrict__ idx2,
                float* __restrict__ w0, float* __restrict__ w1, float* __restrict__ w2)
{
#pragma clang fp contract(off)
    const int q = blockIdx.x * 256 + threadIdx.x;
    if (q >= BS) return;
    float d0 = DINF, d1 = DINF, d2 = DINF;
    int   i0 = 0, i1 = 0, i2 = 0;
    // ascending point-range order + strict-< == top_k lowest-index ties
    for (int c = 0; c < nPart; ++c) {
        const size_t off = (size_t)c * BS + q;
        insert3b(d0, d1, d2, i0, i1, i2, pd0[off], pi0[off]);
        insert3b(d0, d1, d2, i0, i1, i2, pd1[off], pi1[off]);
        insert3b(d0, d1, d2, i0, i1, i2, pd2[off], pi2[off]);
    }
    const float r0 = 1.0f / (d0 + 1e-8f);
    const float r1 = 1.0f / (d1 + 1e-8f);
    const float r2 = 1.0f / (d2 + 1e-8f);
    const float sum = (r0 + r1) + r2;            // np sum order
    idx0[q] = i0; idx1[q] = i1; idx2[q] = i2;
    w0[q] = r0 / sum; w1[q] = r1 / sum; w2[q] = r2 / sum;
}

__global__ __launch_bounds__(256)
void interp_kernel(const float* __restrict__ points1,
                   const int* __restrict__ idx0, const int* __restrict__ idx1,
                   const int* __restrict__ idx2,
                   const float* __restrict__ w0, const float* __restrict__ w1,
                   const float* __restrict__ w2,
                   float* __restrict__ out, int N, int S, int D)
{
#pragma clang fp contract(off)
    __shared__ float row[8192];
    const int bd = blockIdx.x;
    const int b  = bd / D;
    const float* __restrict__ src = points1 + (size_t)bd * N;

    for (int i = threadIdx.x * 4; i < N; i += blockDim.x * 4) {
        *reinterpret_cast<float4*>(&row[i]) =
            *reinterpret_cast<const float4*>(src + i);
    }
    __syncthreads();

    float* __restrict__ dst = out + (size_t)bd * S;
    const int qb = b * S;
    for (int s = threadIdx.x; s < S; s += blockDim.x) {
        int q = qb + s;
        float a = row[idx0[q]] * w0[q];
        float c = row[idx1[q]] * w1[q];
        float e = row[idx2[q]] * w2[q];
        dst[s] = (a + c) + e;             // np sum order
    }
}

extern "C" void kernel_launch(void* const* d_in, const int* in_sizes, int n_in,
                              void* d_out, int out_size, void* d_ws, size_t ws_size,
                              hipStream_t stream) {
    const float* xyz1    = (const float*)d_in[0];
    const float* xyz2    = (const float*)d_in[1];
    const float* points1 = (const float*)d_in[2];
    float* out = (float*)d_out;

    const int B = 8;
    const int N = in_sizes[0] / (3 * B);
    const int S = in_sizes[1] / (3 * B);
    const int D = in_sizes[2] / (B * N);
    const int BS = B * S;

    // Prefer 32 chunks of 256 (1024 blocks); fall back to 16x512 if ws tight.
    int nch = 32;
    auto wsNeed = [&](int nc) {
        return (size_t)B * N * 16 + (size_t)nc * BS * 6 * 4 + (size_t)BS * 7 * 4;
    };
    if (wsNeed(32) > ws_size) nch = 16;
    const int cs = N / nch;                   // 256 or 512

    float4* pk  = (float4*)d_ws;
    float*  pd0 = (float*)(pk + (size_t)B * N);
    float*  pd1 = pd0 + (size_t)nch * BS;
    float*  pd2 = pd1 + (size_t)nch * BS;
    int*    pi0 = (int*)(pd2 + (size_t)nch * BS);
    int*    pi1 = pi0 + (size_t)nch * BS;
    int*    pi2 = pi1 + (size_t)nch * BS;
    int*    idx0 = pi2 + (size_t)nch * BS;
    int*    idx1 = idx0 + BS;
    int*    idx2 = idx1 + BS;
    float*  w0   = (float*)(idx2 + BS);
    float*  w1   = w0 + BS;
    float*  w2   = w1 + BS;
    float*  tau  = w2 + BS;

    // tau sub-partials alias pd0..pd2 slots 0..15 (dead before main writes;
    // same-stream ordering guarantees tau3_merge reads first).
    pack_points<<<(B * N + 255) / 256, 256, 0, stream>>>(xyz1, pk, B, N);

    dim3 gt(BS / QT, NSUB);
    knn3_tau<<<gt, QT, 0, stream>>>(pk, xyz2, B, N, S, BS, pd0, pd1, pd2);

    tau3_merge<<<(BS + 255) / 256, 256, 0, stream>>>(pd0, pd1, pd2, BS, tau);

    dim3 gm(BS / (2 * QT), nch);              // 32 x 32 = 1024 blocks
    knn3_main<<<gm, QT, 0, stream>>>(pk, xyz2, tau, B, N, S, BS, cs,
                                     pd0, pd1, pd2, pi0, pi1, pi2);

    knn3_merge<<<(BS + 255) / 256, 256, 0, stream>>>(pd0, pd1, pd2, pi0, pi1, pi2,
                                                     nch, BS,
                                                     idx0, idx1, idx2, w0, w1, w2);

    interp_kernel<<<B * D, 256, 0, stream>>>(points1, idx0, idx1, idx2,
                                             w0, w1, w2, out, N, S, D);
}